// Round 4
// baseline (120.902 us; speedup 1.0000x reference)
//
#include <hip/hip_runtime.h>

// LaplacianReg: B=32, V=65536, K=8, C=3, fp32 in/out.
// res[b,v,c] = ( d[b,v,c] + sum_k w[v,k]*d[b,idx[v,k],c] )^2,  d = out - tgt
//
// Round 4: XCD-local gather. dt re-laid-out as 8 batch-chunks of 4 batches:
//   dt[chunk][v][(b&3)*3+c]  (24 B bf16 row per (chunk,v); 1.57 MB per chunk)
// Pass2 assigns chunk = blockIdx.x & 7 == XCD (empirical round-robin), so each
// XCD's random gathers stay inside its own 1.57 MB chunk -> resident in its
// 4 MiB L2. R0-R3 evidence: gather was saturating IC random-line throughput
// (HBM 8%, VALU 3%, occupancy-doubling null). This converts ~1M random IC
// lines -> XCD-local L2 hits. Mapping is a perf heuristic only; correctness
// does not depend on block->XCD assignment.
#define BB 32
#define VV 65536
#define KK 8
#define CC 3

constexpr int NCHUNK = 8;             // batch chunks (== XCDs)
constexpr int CB     = BB / NCHUNK;   // 4 batches per chunk
constexpr int CROW   = CB * CC;       // 12 elems per (chunk,v) row = 24 B
constexpr int CROWU  = CROW / 2;      // 6 uints per row

// ---- pass1 tile ----
constexpr int TV1   = 64;
constexpr int ROW   = BB * CC;        // 96
constexpr int PROW1 = ROW + 1;        // 97, LDS pad
constexpr int T1ELEMS = TV1 * ROW;    // 6144

// ---- pass2 tile ----
constexpr int TV2   = 128;            // v per block (2 lanes per v = 256 thr)
constexpr int PROW2 = CROW + 1;       // 13

__device__ __forceinline__ unsigned int f2bf(float f) {
  unsigned int u = __float_as_uint(f);
  u += 0x7FFFu + ((u >> 16) & 1u);    // round-to-nearest-even
  return u >> 16;
}
__device__ __forceinline__ float bflo(unsigned int u) { return __uint_as_float(u << 16); }
__device__ __forceinline__ float bfhi(unsigned int u) { return __uint_as_float(u & 0xFFFF0000u); }

struct U3 { unsigned int x, y, z; };  // 12B, 4B-aligned -> global_load_dwordx3

// ---------------------------------------------------------------------------
// Pass 1: dt[chunk][v][j] = bf16(out[b,v,c]-tgt[b,v,c]), chunk=b/4, j=(b&3)*3+c.
// Coalesced float4 reads, LDS transpose, coalesced uint4 writes per chunk
// region (TV1*24B = 1536B contiguous per chunk per block).
// ---------------------------------------------------------------------------
__global__ __launch_bounds__(256) void lap_pass1_transpose_sub(
    const float* __restrict__ outp, const float* __restrict__ tgtp,
    unsigned int* __restrict__ dt) {
  __shared__ float tile[TV1 * PROW1];   // 24.8 KB
  const int t  = threadIdx.x;
  const int v0 = blockIdx.x * TV1;

  const float4* o4 = (const float4*)outp;
  const float4* t4 = (const float4*)tgtp;
  const int src_base4 = (v0 * CC) >> 2;           // exact: v0*CC % 4 == 0
  #pragma unroll
  for (int l4 = t; l4 < T1ELEMS / 4; l4 += 256) {
    int b  = l4 / (TV1 * CC / 4);                 // 48 float4 per b
    int j4 = l4 - b * (TV1 * CC / 4);
    int src = b * (VV * CC / 4) + src_base4 + j4;
    float4 a = o4[src];
    float4 g = t4[src];
    float dv[4] = {a.x - g.x, a.y - g.y, a.z - g.z, a.w - g.w};
    int j = 4 * j4;
    #pragma unroll
    for (int q = 0; q < 4; q++) {
      int jj = j + q;
      int vrel = jj / CC, c = jj - vrel * CC;
      tile[vrel * PROW1 + b * CC + c] = dv[q];
    }
  }
  __syncthreads();

  // Per chunk: region of TV1 rows x 24B = 96 uint4, contiguous in dt.
  // 8 chunks x 96 = 768 uint4 per block; 256 threads x 3 iters.
  #pragma unroll
  for (int u = t; u < NCHUNK * (TV1 * CROWU / 4); u += 256) {
    int chunk = u / (TV1 * CROWU / 4);            // /96
    int i16   = u - chunk * (TV1 * CROWU / 4);
    int E = i16 * 8;                              // elem index in chunk region
    unsigned int w[8];
    #pragma unroll
    for (int q = 0; q < 8; q++) {
      int ee = E + q;
      int vrel = ee / CROW, jj = ee - vrel * CROW;
      w[q] = f2bf(tile[vrel * PROW1 + chunk * CROW + jj]);
    }
    uint4 o;
    o.x = w[0] | (w[1] << 16);
    o.y = w[2] | (w[3] << 16);
    o.z = w[4] | (w[5] << 16);
    o.w = w[6] | (w[7] << 16);
    uint4* dst = (uint4*)(dt + (size_t)chunk * (VV * CROWU) + (size_t)v0 * CROWU);
    dst[i16] = o;
  }
}

// ---------------------------------------------------------------------------
// Pass 2: chunk = bid & 7 (== XCD), v-tile = bid >> 3. 2 lanes per v, lane l
// covers batches chunk*4 + {2l, 2l+1} (6 bf16 = one dwordx3 per gather row).
// All gathers land in the XCD's own 1.57 MB dt chunk -> local L2 hits.
// Output restaged via LDS for coalesced fp32 float4 writes in (B,V,C).
// ---------------------------------------------------------------------------
__global__ __launch_bounds__(256) void lap_pass2_gather(
    const unsigned int* __restrict__ dt, const int* __restrict__ nidx,
    const float* __restrict__ nw, float* __restrict__ res) {
  __shared__ float rtile[TV2 * PROW2];  // 6.7 KB
  __shared__ int   idx_s[TV2 * KK];     // 4 KB
  __shared__ float w_s[TV2 * KK];       // 4 KB
  const int t     = threadIdx.x;
  const int chunk = blockIdx.x & (NCHUNK - 1);
  const int v0    = (blockIdx.x >> 3) * TV2;

  // Stage idx/w: 1024 ints each; 256 threads x int4/float4.
  ((int4*)idx_s)[t]  = ((const int4*)(nidx + (size_t)v0 * KK))[t];
  ((float4*)w_s)[t]  = ((const float4*)(nw + (size_t)v0 * KK))[t];
  __syncthreads();

  const unsigned int* dtc = dt + (size_t)chunk * (VV * CROWU);
  const int vrel = t >> 1;
  const int l    = t & 1;             // lane within pair; b = chunk*4 + 2l,2l+1
  const int v    = v0 + vrel;

  // idx/w broadcast within pair.
  const int4*   ip = (const int4*)&idx_s[vrel * KK];
  const float4* wp = (const float4*)&w_s[vrel * KK];
  int4   ia = ip[0], ib = ip[1];
  float4 wa = wp[0], wb = wp[1];
  int   nbk[KK] = {ia.x, ia.y, ia.z, ia.w, ib.x, ib.y, ib.z, ib.w};
  float wk[KK]  = {wa.x, wa.y, wa.z, wa.w, wb.x, wb.y, wb.z, wb.w};

  // self term (dwordx3)
  U3 s = *(const U3*)(dtc + (size_t)v * CROWU + 3 * l);
  float x0 = bflo(s.x), y0 = bfhi(s.x), z0 = bflo(s.y);
  float x1 = bfhi(s.y), y1 = bflo(s.z), z1 = bfhi(s.z);

  #pragma unroll
  for (int k = 0; k < KK; k++) {
    U3 u = *(const U3*)(dtc + (size_t)nbk[k] * CROWU + 3 * l);
    const float wt = wk[k];
    x0 = fmaf(wt, bflo(u.x), x0);
    y0 = fmaf(wt, bfhi(u.x), y0);
    z0 = fmaf(wt, bflo(u.y), z0);
    x1 = fmaf(wt, bfhi(u.y), x1);
    y1 = fmaf(wt, bflo(u.z), y1);
    z1 = fmaf(wt, bfhi(u.z), z1);
  }
  float* rp = &rtile[vrel * PROW2 + 6 * l];  // (b=2l,c0..2),(b=2l+1,c0..2)
  rp[0] = x0 * x0; rp[1] = y0 * y0; rp[2] = z0 * z0;
  rp[3] = x1 * x1; rp[4] = y1 * y1; rp[5] = z1 * z1;
  __syncthreads();

  // Coalesced writeback: 4 batches x 96 float4 (contiguous 1536B per batch).
  float4* r4 = (float4*)res;
  const int dst_base4 = (v0 * CC) >> 2;       // v0*3/4, exact
  #pragma unroll
  for (int l4 = t; l4 < CB * (TV2 * CC / 4); l4 += 256) {
    int b  = l4 / (TV2 * CC / 4);             // 96 float4 per batch
    int j4 = l4 - b * (TV2 * CC / 4);
    int bg = chunk * CB + b;
    int j  = 4 * j4;
    float tmp[4];
    #pragma unroll
    for (int q = 0; q < 4; q++) {
      int jj = j + q;
      int vr = jj / CC, c = jj - vr * CC;
      tmp[q] = rtile[vr * PROW2 + b * CC + c];
    }
    r4[bg * (VV * CC / 4) + dst_base4 + j4] = make_float4(tmp[0], tmp[1], tmp[2], tmp[3]);
  }
}

// ---------------------------------------------------------------------------
// Fallback (ws too small): fused fp32 direct kernel, one thread per (b,v).
// ---------------------------------------------------------------------------
__global__ __launch_bounds__(256) void lap_fused_fallback(
    const float* __restrict__ outp, const float* __restrict__ tgtp,
    const int* __restrict__ nidx, const float* __restrict__ nw,
    float* __restrict__ res) {
  int tid = blockIdx.x * 256 + threadIdx.x;
  if (tid >= BB * VV) return;
  int v = tid & (VV - 1);
  int b = tid >> 16;
  float ax = 0.f, ay = 0.f, az = 0.f;
  #pragma unroll
  for (int k = 0; k < KK; k++) {
    int   nb = nidx[v * KK + k];
    float wt = nw[v * KK + k];
    const float* po = outp + ((size_t)b * VV + nb) * CC;
    const float* pt = tgtp + ((size_t)b * VV + nb) * CC;
    ax = fmaf(wt, po[0] - pt[0], ax);
    ay = fmaf(wt, po[1] - pt[1], ay);
    az = fmaf(wt, po[2] - pt[2], az);
  }
  const float* so = outp + (size_t)tid * CC;
  const float* st = tgtp + (size_t)tid * CC;
  float dx = so[0] - st[0] + ax;
  float dy = so[1] - st[1] + ay;
  float dz = so[2] - st[2] + az;
  float* rp = res + (size_t)tid * CC;
  rp[0] = dx * dx; rp[1] = dy * dy; rp[2] = dz * dz;
}

extern "C" void kernel_launch(void* const* d_in, const int* in_sizes, int n_in,
                              void* d_out, int out_size, void* d_ws, size_t ws_size,
                              hipStream_t stream) {
  const float* outp = (const float*)d_in[0];
  const float* tgtp = (const float*)d_in[1];
  const int*   nidx = (const int*)d_in[2];
  const float* nw   = (const float*)d_in[3];
  float* res = (float*)d_out;

  const size_t dt_bytes = (size_t)VV * ROW * 2;   // 12.6 MB bf16
  if (ws_size >= dt_bytes) {
    unsigned int* dt = (unsigned int*)d_ws;
    lap_pass1_transpose_sub<<<VV / TV1, 256, 0, stream>>>(outp, tgtp, dt);
    lap_pass2_gather<<<NCHUNK * (VV / TV2), 256, 0, stream>>>(dt, nidx, nw, res);
  } else {
    lap_fused_fallback<<<(BB * VV) / 256, 256, 0, stream>>>(outp, tgtp, nidx, nw, res);
  }
}

// Round 5
// 117.075 us; speedup vs baseline: 1.0327x; 1.0327x over previous
//
#include <hip/hip_runtime.h>
#include <hip/hip_cooperative_groups.h>

namespace cg = cooperative_groups;

// LaplacianReg: B=32, V=65536, K=8, C=3, fp32 in/out.
// res[b,v,c] = ( d[b,v,c] + sum_k w[v,k]*d[b,idx[v,k],c] )^2,  d = out - tgt
//
// Round 5: fused coop (R1, best measured) + TV=32 (8 blocks/CU co-resident)
// + self term read fp32 from the block's own LDS tile (phase1 residue):
// removes 1/9 of gather requests, removes a dependent global load, and makes
// the self term exact (bf16 only on neighbor terms).
#define BB 32
#define VV 65536
#define KK 8
#define CC 3

constexpr int TV   = 32;              // v-tile per block (grid 2048)
constexpr int ROW  = BB * CC;         // 96 elems per transposed v-row
constexpr int PROW = ROW + 1;         // LDS pad
constexpr int TILE_ELEMS = TV * ROW;  // 3072
constexpr int ROWU = ROW / 2;         // 48 uints per bf16 row (192B)

__device__ __forceinline__ unsigned int f2bf(float f) {
  unsigned int u = __float_as_uint(f);
  u += 0x7FFFu + ((u >> 16) & 1u);    // round-to-nearest-even
  return u >> 16;
}
__device__ __forceinline__ float bflo(unsigned int u) { return __uint_as_float(u << 16); }
__device__ __forceinline__ float bfhi(unsigned int u) { return __uint_as_float(u & 0xFFFF0000u); }

struct U3 { unsigned int x, y, z; };  // 12B, 4B-aligned -> global_load_dwordx3

// ---------------------------------------------------------------------------
// Phase 1: tile[vrel][b*3+c] = d (fp32, kept for self term);
//          dt[v][b][c] = bf16(d), coalesced uint4 writes.
// ---------------------------------------------------------------------------
__device__ __forceinline__ void do_transpose_sub(
    const float* __restrict__ outp, const float* __restrict__ tgtp,
    unsigned int* __restrict__ dt, float* tile, int v0, int t) {
  const float4* o4 = (const float4*)outp;
  const float4* t4 = (const float4*)tgtp;
  const int src_base4 = (v0 * CC) >> 2;           // exact: v0 multiple of 32
  #pragma unroll
  for (int l4 = t; l4 < TILE_ELEMS / 4; l4 += 256) {
    int b  = l4 / (TV * CC / 4);                  // 24 float4 per b
    int j4 = l4 - b * (TV * CC / 4);
    int src = b * (VV * CC / 4) + src_base4 + j4;
    float4 a = o4[src];
    float4 g = t4[src];
    float dv[4] = {a.x - g.x, a.y - g.y, a.z - g.z, a.w - g.w};
    int j = 4 * j4;
    #pragma unroll
    for (int q = 0; q < 4; q++) {
      int jj = j + q;
      int vrel = jj / CC, c = jj - vrel * CC;
      tile[vrel * PROW + b * CC + c] = dv[q];
    }
  }
  __syncthreads();

  // Pack 8 consecutive elems -> uint4 of bf16 pairs. 8 | 96, never crosses rows.
  uint4* dst = (uint4*)(dt + (size_t)v0 * ROWU);  // byte offset v0*192, 16B aligned
  #pragma unroll
  for (int i8 = t; i8 < TILE_ELEMS / 8; i8 += 256) {
    int e = i8 * 8;
    int vrel = e / ROW, r = e - vrel * ROW;
    const float* p = &tile[vrel * PROW + r];
    uint4 o;
    o.x = f2bf(p[0]) | (f2bf(p[1]) << 16);
    o.y = f2bf(p[2]) | (f2bf(p[3]) << 16);
    o.z = f2bf(p[4]) | (f2bf(p[5]) << 16);
    o.w = f2bf(p[6]) | (f2bf(p[7]) << 16);
    dst[i8] = o;
  }
}

// ---------------------------------------------------------------------------
// Phase 2: 16-lane group per v, lane l covers batches 2l,2l+1. Self term is
// read fp32 from this block's LDS tile (phase-1 residue) -- only the 8
// neighbor rows are gathered from dt (dwordx3 each). Squares overwrite the
// same LDS slots in place; coalesced float4 writeback to (B,V,C).
// ---------------------------------------------------------------------------
__device__ __forceinline__ void do_gather(
    const unsigned int* __restrict__ dt, const int* __restrict__ nidx,
    const float* __restrict__ nw, float* __restrict__ res,
    float* tile, int v0, int t) {
  const int g = t >> 4;   // 16 groups per block
  const int l = t & 15;   // lane within group; covers b = 2l, 2l+1
  #pragma unroll
  for (int i = 0; i < TV / 16; i++) {
    const int vrel = i * 16 + g;
    const int v    = v0 + vrel;

    // Group-uniform idx/w: 16 lanes share the address -> broadcast loads.
    const int4*   ip = (const int4*)(nidx + (size_t)v * KK);
    const float4* wp = (const float4*)(nw + (size_t)v * KK);
    int4   ia = ip[0], ib = ip[1];
    float4 wa = wp[0], wb = wp[1];
    int   nbk[KK] = {ia.x, ia.y, ia.z, ia.w, ib.x, ib.y, ib.z, ib.w};
    float wk[KK]  = {wa.x, wa.y, wa.z, wa.w, wb.x, wb.y, wb.z, wb.w};

    // self term: fp32 from LDS (phase-1 tile holds d for this v-tile)
    float* sp = &tile[vrel * PROW + 6 * l];
    float x0 = sp[0], y0 = sp[1], z0 = sp[2];
    float x1 = sp[3], y1 = sp[4], z1 = sp[5];

    #pragma unroll
    for (int k = 0; k < KK; k++) {
      U3 u = *(const U3*)(dt + (size_t)nbk[k] * ROWU + 3 * l);
      const float wt = wk[k];
      x0 = fmaf(wt, bflo(u.x), x0);
      y0 = fmaf(wt, bfhi(u.x), y0);
      z0 = fmaf(wt, bflo(u.y), z0);
      x1 = fmaf(wt, bfhi(u.y), x1);
      y1 = fmaf(wt, bflo(u.z), y1);
      z1 = fmaf(wt, bfhi(u.z), z1);
    }
    // squares overwrite the same 6 slots (thread-private; rows disjoint per i)
    sp[0] = x0 * x0; sp[1] = y0 * y0; sp[2] = z0 * z0;
    sp[3] = x1 * x1; sp[4] = y1 * y1; sp[5] = z1 * z1;
  }
  __syncthreads();

  // Coalesced writeback to (B,V,C).
  float4* r4 = (float4*)res;
  const int dst_base4 = (v0 * CC) >> 2;
  #pragma unroll
  for (int l4 = t; l4 < TILE_ELEMS / 4; l4 += 256) {
    int b  = l4 / (TV * CC / 4);
    int j4 = l4 - b * (TV * CC / 4);
    int j  = 4 * j4;
    float tmp[4];
    #pragma unroll
    for (int q = 0; q < 4; q++) {
      int jj = j + q;
      int vrel = jj / CC, c = jj - vrel * CC;
      tmp[q] = tile[vrel * PROW + b * CC + c];
    }
    r4[b * (VV * CC / 4) + dst_base4 + j4] = make_float4(tmp[0], tmp[1], tmp[2], tmp[3]);
  }
}

// ---------------------------------------------------------------------------
// Fused cooperative kernel: phase1 -> fence -> grid sync -> phase2.
// grid = 2048 blocks; launch_bounds(256,8) => VGPR<=64, 14.4KB LDS => 8
// blocks/CU so all 2048 are co-resident (gated by occupancy query on host).
// ---------------------------------------------------------------------------
__global__ __launch_bounds__(256, 8) void lap_fused_coop(
    const float* __restrict__ outp, const float* __restrict__ tgtp,
    const int* __restrict__ nidx, const float* __restrict__ nw,
    unsigned int* __restrict__ dt, float* __restrict__ res) {
  __shared__ float smem[TV * PROW];   // 12.4 KB, lives across both phases
  const int t  = threadIdx.x;
  const int v0 = blockIdx.x * TV;

  do_transpose_sub(outp, tgtp, dt, smem, v0, t);
  __threadfence();                    // push dt to device scope (XCD L2s)
  cg::this_grid().sync();
  do_gather(dt, nidx, nw, res, smem, v0, t);
}

// --------------------------- fallback: two kernels (R3, proven) ------------
__global__ __launch_bounds__(256) void lap_pass1_transpose_sub(
    const float* __restrict__ outp, const float* __restrict__ tgtp,
    unsigned int* __restrict__ dt) {
  __shared__ float tile[TV * PROW];
  do_transpose_sub(outp, tgtp, dt, tile, blockIdx.x * TV, threadIdx.x);
}

__global__ __launch_bounds__(256) void lap_pass2_gather(
    const unsigned int* __restrict__ dt, const int* __restrict__ nidx,
    const float* __restrict__ nw, float* __restrict__ res) {
  __shared__ float rtile[TV * PROW];
  const int t  = threadIdx.x;
  const int v0 = blockIdx.x * TV;
  // rebuild self terms from dt (no phase-1 residue in split mode)
  const int g = t >> 4, l = t & 15;
  #pragma unroll
  for (int i = 0; i < TV / 16; i++) {
    const int vrel = i * 16 + g;
    const int v    = v0 + vrel;
    U3 s = *(const U3*)(dt + (size_t)v * ROWU + 3 * l);
    float* sp = &rtile[vrel * PROW + 6 * l];
    sp[0] = bflo(s.x); sp[1] = bfhi(s.x); sp[2] = bflo(s.y);
    sp[3] = bfhi(s.y); sp[4] = bflo(s.z); sp[5] = bfhi(s.z);
  }
  __syncthreads();
  do_gather(dt, nidx, nw, res, rtile, v0, t);
}

// ---------------------------------------------------------------------------
// Fallback (ws too small): fused fp32 direct kernel, one thread per (b,v).
// ---------------------------------------------------------------------------
__global__ __launch_bounds__(256) void lap_fused_fallback(
    const float* __restrict__ outp, const float* __restrict__ tgtp,
    const int* __restrict__ nidx, const float* __restrict__ nw,
    float* __restrict__ res) {
  int tid = blockIdx.x * 256 + threadIdx.x;
  if (tid >= BB * VV) return;
  int v = tid & (VV - 1);
  int b = tid >> 16;
  float ax = 0.f, ay = 0.f, az = 0.f;
  #pragma unroll
  for (int k = 0; k < KK; k++) {
    int   nb = nidx[v * KK + k];
    float wt = nw[v * KK + k];
    const float* po = outp + ((size_t)b * VV + nb) * CC;
    const float* pt = tgtp + ((size_t)b * VV + nb) * CC;
    ax = fmaf(wt, po[0] - pt[0], ax);
    ay = fmaf(wt, po[1] - pt[1], ay);
    az = fmaf(wt, po[2] - pt[2], az);
  }
  const float* so = outp + (size_t)tid * CC;
  const float* st = tgtp + (size_t)tid * CC;
  float dx = so[0] - st[0] + ax;
  float dy = so[1] - st[1] + ay;
  float dz = so[2] - st[2] + az;
  float* rp = res + (size_t)tid * CC;
  rp[0] = dx * dx; rp[1] = dy * dy; rp[2] = dz * dz;
}

extern "C" void kernel_launch(void* const* d_in, const int* in_sizes, int n_in,
                              void* d_out, int out_size, void* d_ws, size_t ws_size,
                              hipStream_t stream) {
  const float* outp = (const float*)d_in[0];
  const float* tgtp = (const float*)d_in[1];
  const int*   nidx = (const int*)d_in[2];
  const float* nw   = (const float*)d_in[3];
  float* res = (float*)d_out;

  const size_t dt_bytes = (size_t)VV * ROW * 2;   // 12.6 MB bf16
  if (ws_size >= dt_bytes) {
    unsigned int* dt = (unsigned int*)d_ws;

    static int coop = -1;   // decided once (at capture); replays reuse the graph
    if (coop < 0) {
      int nb = 0;
      hipError_t e = hipOccupancyMaxActiveBlocksPerMultiprocessor(
          &nb, lap_fused_coop, 256, 0);
      // need 8 blocks/CU so all 2048 blocks are co-resident on 256 CUs
      coop = (e == hipSuccess && nb >= 8) ? 1 : 0;
    }
    if (coop == 1) {
      void* params[] = {(void*)&outp, (void*)&tgtp, (void*)&nidx,
                        (void*)&nw,   (void*)&dt,   (void*)&res};
      hipError_t e = hipLaunchCooperativeKernel(
          lap_fused_coop, dim3(VV / TV), dim3(256), params, 0u, stream);
      if (e == hipSuccess) return;
      coop = 0;  // fall through to two-kernel path
    }
    lap_pass1_transpose_sub<<<VV / TV, 256, 0, stream>>>(outp, tgtp, dt);
    lap_pass2_gather<<<VV / TV, 256, 0, stream>>>(dt, nidx, nw, res);
  } else {
    lap_fused_fallback<<<(BB * VV) / 256, 256, 0, stream>>>(outp, tgtp, nidx, nw, res);
  }
}